// Round 1
// 4167.054 us; speedup vs baseline: 1.0457x; 1.0457x over previous
//
#include <hip/hip_runtime.h>
#include <hip/hip_cooperative_groups.h>

namespace cg = cooperative_groups;

__device__ __forceinline__ float sigf(float x) { return 1.0f / (1.0f + __expf(-x)); }

// ---------------- transpose: out[c*out_ld + r] = in[r*C + c] (used for atk_W only) ----
__global__ void __launch_bounds__(256) transpose_kernel(
    const float* __restrict__ in, float* __restrict__ out, int R, int C, int out_ld)
{
    __shared__ float tl[32][33];
    int tx = threadIdx.x, ty = threadIdx.y;             // block (32,8)
    int c0 = blockIdx.x * 32, r0 = blockIdx.y * 32;
#pragma unroll
    for (int i = 0; i < 4; i++) {
        int r = r0 + ty + i * 8, c = c0 + tx;
        if (r < R && c < C) tl[ty + i * 8][tx] = in[(size_t)r * C + c];
    }
    __syncthreads();
#pragma unroll
    for (int i = 0; i < 4; i++) {
        int c = c0 + ty + i * 8, r = r0 + tx;
        if (r < R && c < C) out[(size_t)c * out_ld + r] = tl[tx][ty + i * 8];
    }
}

__global__ void __launch_bounds__(256) prep_bcomb(const float* __restrict__ b_ih,
                                                  const float* __restrict__ b_hh,
                                                  float* __restrict__ bcomb)
{
    int i = blockIdx.x * 256 + threadIdx.x;
    if (i < 2048) bcomb[i] = b_ih[i] + b_hh[i];
}

// ---------------- generic NT GEMM: C[m][j] = sum_k A[m][k]*B[j][k] + bias[j] ----------
template <int GATHER, int REMAP>
__global__ void __launch_bounds__(256) gemm_nt(
    const float* __restrict__ A, int lda, const float* __restrict__ B, int ldb,
    const int* __restrict__ caps, const float* __restrict__ bias,
    float* __restrict__ C, int ldc, int J, int K)
{
    __shared__ float la[32 * 132];      // [kk][m], pad 128->132
    __shared__ float lb[32 * 68];       // [kk][j], pad 64->68
    const int tid = threadIdx.x;
    const int m0 = blockIdx.x * 128, j0 = blockIdx.y * 64;
    const int tx = tid & 15, ty = tid >> 4;
    float acc[8][4] = {};

    for (int k0 = 0; k0 < K; k0 += 32) {
        __syncthreads();
        {   // stage A: 128 rows x 32 k, transposed into la
            int r0 = tid >> 3, c4 = (tid & 7) * 4;
#pragma unroll
            for (int p = 0; p < 4; p++) {
                int m = m0 + r0 + p * 32;
                int arow = GATHER ? caps[(m & 63) * 32 + (m >> 6)] : m;
                const float4 v = *(const float4*)&A[(size_t)arow * lda + k0 + c4];
#pragma unroll
                for (int q = 0; q < 4; q++) la[(c4 + q) * 132 + r0 + p * 32] = ((const float*)&v)[q];
            }
        }
        {   // stage B: 64 j-rows x 32 k, transposed into lb
            int r0 = tid >> 3, c4 = (tid & 7) * 4;
#pragma unroll
            for (int p = 0; p < 2; p++) {
                int j = j0 + r0 + p * 32;
                if (j >= J) j = J - 1;
                const float4 v = *(const float4*)&B[(size_t)j * ldb + k0 + c4];
#pragma unroll
                for (int q = 0; q < 4; q++) lb[(c4 + q) * 68 + r0 + p * 32] = ((const float*)&v)[q];
            }
        }
        __syncthreads();
#pragma unroll
        for (int kk = 0; kk < 32; kk++) {
            float bv[4];
            *(float4*)bv = *(const float4*)&lb[kk * 68 + tx * 4];
#pragma unroll
            for (int pi = 0; pi < 2; pi++) {
                float av[4];
                *(float4*)av = *(const float4*)&la[kk * 132 + ty * 8 + pi * 4];
#pragma unroll
                for (int i = 0; i < 4; i++)
#pragma unroll
                    for (int jj = 0; jj < 4; jj++)
                        acc[pi * 4 + i][jj] += av[i] * bv[jj];
            }
        }
    }
    const int j = j0 + tx * 4;
#pragma unroll
    for (int pi = 0; pi < 2; pi++)
#pragma unroll
        for (int i = 0; i < 4; i++) {
            int m = m0 + ty * 8 + pi * 4 + i;
            int orow = REMAP ? ((m & 63) * 32 + (m >> 6)) : m;
#pragma unroll
            for (int jj = 0; jj < 4; jj++)
                if (j + jj < J)
                    C[(size_t)orow * ldc + j + jj] = acc[pi * 4 + i][jj] + bias[j + jj];
        }
}

// ---------------- init GEMM: [h0|c0] partials.  grid (16 j-tiles, 48 k-chunks) --------
__global__ void __launch_bounds__(256) init_gemm(
    const float* __restrict__ features, const float* __restrict__ Wh,
    const float* __restrict__ Wc, float* __restrict__ ipart)
{
    __shared__ float la[32 * 68];
    __shared__ float lb[32 * 68];
    const int tid = threadIdx.x;
    const int jg0 = blockIdx.x * 64, kc = blockIdx.y;
    const float* Bsrc = (jg0 < 512) ? Wh : Wc;
    const int j0 = (jg0 < 512) ? jg0 : jg0 - 512;
    const int tx = tid & 15, ty = tid >> 4;
    float acc[4][4] = {};

    for (int kt = 0; kt < 64; kt++) {
        const int k0 = kc * 2048 + kt * 32;
        __syncthreads();
        {   // A: features, 64 rows, lda 98304 (transposed store)
            int r0 = tid >> 3, c4 = (tid & 7) * 4;
#pragma unroll
            for (int p = 0; p < 2; p++) {
                const float4 v = *(const float4*)&features[(size_t)(r0 + p * 32) * 98304 + k0 + c4];
#pragma unroll
                for (int q = 0; q < 4; q++) la[(c4 + q) * 68 + r0 + p * 32] = ((const float*)&v)[q];
            }
        }
        {   // B: k-major [98304][512]; direct b128 store
            int kr = tid >> 4, j4 = (tid & 15) * 4;
#pragma unroll
            for (int p = 0; p < 2; p++) {
                const float4 v = *(const float4*)&Bsrc[(size_t)(k0 + kr + p * 16) * 512 + j0 + j4];
                *(float4*)&lb[(kr + p * 16) * 68 + j4] = v;
            }
        }
        __syncthreads();
#pragma unroll
        for (int kk = 0; kk < 32; kk++) {
            float av[4], bv[4];
            *(float4*)av = *(const float4*)&la[kk * 68 + ty * 4];
            *(float4*)bv = *(const float4*)&lb[kk * 68 + tx * 4];
#pragma unroll
            for (int i = 0; i < 4; i++)
#pragma unroll
                for (int jj = 0; jj < 4; jj++) acc[i][jj] += av[i] * bv[jj];
        }
    }
#pragma unroll
    for (int i = 0; i < 4; i++) {
        int m = ty * 4 + i;
#pragma unroll
        for (int jj = 0; jj < 4; jj++)
            ipart[(size_t)(kc * 64 + m) * 1024 + jg0 + tx * 4 + jj] = acc[i][jj];
    }
}

// ---------------- reduce init partials -> h0 (into xh[., 1536:2048]) and c0 -----------
__global__ void __launch_bounds__(256) init_reduce(const float* __restrict__ ipart,
                                                   float* __restrict__ xh,
                                                   float* __restrict__ cbuf)
{
    int idx = blockIdx.x * 256 + threadIdx.x;   // 65536
    int n = idx >> 10, jg = idx & 1023;
    float s = 0.0f;
#pragma unroll 8
    for (int kc = 0; kc < 48; kc++) s += ipart[(size_t)(kc * 64 + n) * 1024 + jg];
    if (jg < 512) xh[(size_t)n * 2048 + 1536 + jg] = s;
    else          cbuf[(size_t)n * 512 + (jg - 512)] = s;
}

// ---------------- fused sequential loop: ONE cooperative kernel for all 32 steps ------
// grid 256 x 1024 threads (1 block/CU, 16 waves). Per step:
//   blocks 0-63  : LSTM update (gates t-1) -> h; attn_h; scores; softmax; ctx -> xh
//   grid.sync()  : xh visible
//   all 256      : gates GEMM tile (jt=blk>>3, kc=blk&7), 4-way k-split -> 32 partials
//   grid.sync()  : gpart visible
__global__ void __launch_bounds__(1024) loop_kernel(
    const float* __restrict__ features, const float* __restrict__ attn_img,
    const float* __restrict__ AtkWT, const float* __restrict__ atk_b,
    const float* __restrict__ full_W, const float* __restrict__ full_b,
    const float* __restrict__ emb_part, const float* __restrict__ W_ih,
    const float* __restrict__ W_hh, float* __restrict__ gpart,
    float* __restrict__ xh, float* __restrict__ cbuf, float* __restrict__ h_out)
{
    __shared__ float la[32 * 68];     // gates A stage [kk][m]
    __shared__ float lb[32 * 68];     // gates B stage [kk][j]
    __shared__ float lds_h[512];
    __shared__ float lds_ah[512];
    __shared__ float lds_fw[512];
    __shared__ float lds_red[64];
    __shared__ float lds_logit[64];
    __shared__ float gbuf[2048];      // gate sums / attn_h partials

    cg::grid_group grid = cg::this_grid();
    const int blk = blockIdx.x, tid = threadIdx.x;
    const int n = blk;                              // valid when blk < 64
    const int jt = blk >> 3, kc = blk & 7;          // gates tile
    const int j0 = jt * 64;
    const int gq = tid >> 8, ltid = tid & 255;      // 4 k-groups of 256 threads
    const int tx = ltid & 15, ty = ltid >> 4;
    const int sr = tid >> 4, skk2 = (tid & 15) * 2; // staging row / k-pair

    if (blk < 64 && tid < 512) lds_fw[tid] = full_W[tid];   // hoisted, sync'd below

    for (int t = 0; t < 32; ++t) {
        if (blk < 64) {
            if (t > 0) {
                // ---- LSTM update from gate partials of step t-1 ----
                for (int idx = tid; idx < 2048; idx += 1024) {
                    float s = emb_part[(size_t)((t - 1) * 64 + n) * 2048 + idx];
#pragma unroll 8
                    for (int s32 = 0; s32 < 32; s32++)
                        s += gpart[(size_t)(s32 * 64 + n) * 2048 + idx];
                    gbuf[idx] = s;
                }
                __syncthreads();
                if (tid < 512) {
                    float cold = cbuf[(size_t)n * 512 + tid];
                    float cn = sigf(gbuf[512 + tid]) * cold + sigf(gbuf[tid]) * tanhf(gbuf[1024 + tid]);
                    float hn = sigf(gbuf[1536 + tid]) * tanhf(cn);
                    cbuf[(size_t)n * 512 + tid] = cn;
                    xh[(size_t)n * 2048 + 1536 + tid] = hn;
                    h_out[(size_t)((t - 1) * 64 + n) * 512 + tid] = hn;
                    lds_h[tid] = hn;
                }
            } else {
                if (tid < 512) lds_h[tid] = xh[(size_t)n * 2048 + 1536 + tid];
            }
            __syncthreads();    // lds_h ready; gbuf free

            // ---- attn_h[a] = atk_b[a] + sum_k h[k]*AtkWT[k][a], 2-way k-split ----
            {
                const int a = tid & 511, half = tid >> 9;
                const float* col = AtkWT + (size_t)(half * 256) * 512 + a;
                const float* hp = lds_h + half * 256;
                float s = 0.0f;
#pragma unroll 8
                for (int k = 0; k < 256; k++) s += hp[k] * col[(size_t)k * 512];
                gbuf[half * 512 + a] = s;
            }
            __syncthreads();
            if (tid < 512) lds_ah[tid] = atk_b[tid] + gbuf[tid] + gbuf[512 + tid];
            __syncthreads();

            // ---- scores[p]: one wave per p (16 waves x 4 rounds) ----
            {
                const int w = tid >> 6, lane = tid & 63;
#pragma unroll
                for (int i = 0; i < 4; i++) {
                    const int p = i * 16 + w;
                    const float* img = attn_img + (size_t)(n * 64 + p) * 512;
                    float part = 0.0f;
#pragma unroll
                    for (int jx = 0; jx < 8; jx++) {
                        int a = lane + jx * 64;
                        part += fmaxf(lds_ah[a] + img[a], 0.0f) * lds_fw[a];
                    }
#pragma unroll
                    for (int off = 32; off > 0; off >>= 1) part += __shfl_down(part, off, 64);
                    if (lane == 0) lds_red[p] = part;
                }
            }
            __syncthreads();

            // ---- softmax over p ----
            if (tid < 64) {
                float s = lds_red[tid] + full_b[0];
                float m = s;
#pragma unroll
                for (int off = 32; off > 0; off >>= 1) m = fmaxf(m, __shfl_xor(m, off, 64));
                float e = __expf(s - m);
                float sum = e;
#pragma unroll
                for (int off = 32; off > 0; off >>= 1) sum += __shfl_xor(sum, off, 64);
                lds_logit[tid] = e / sum;
            }
            __syncthreads();

            // ---- ctx[c] = sum_p logit[p]*features[n,p,c] -> xh[n][0:1536] ----
            for (int cc = tid; cc < 1536; cc += 1024) {
                const float* f = features + (size_t)(n * 64) * 1536 + cc;
                float acc = 0.0f;
#pragma unroll 16
                for (int p = 0; p < 64; p++) acc += lds_logit[p] * f[(size_t)p * 1536];
                xh[(size_t)n * 2048 + cc] = acc;
            }
        }
        grid.sync();    // xh (ctx + h) visible to all blocks

        // ---- gates GEMM: C_part = xh[64 x 256-chunk] @ W^T, 4-way k-split ----
        {
            float acc[4][4] = {};
            float2 pa, pb;
            {   // prefetch kt=0 (T14: issue-early)
                const int k0 = kc * 256;
                pa = *(const float2*)&xh[(size_t)sr * 2048 + k0 + skk2];
                const int kg = k0 + skk2;
                const float* src = (kg < 1536) ? &W_ih[(size_t)(j0 + sr) * 2048 + kg]
                                               : &W_hh[(size_t)(j0 + sr) * 512 + kg - 1536];
                pb = *(const float2*)src;
            }
            for (int kt = 0; kt < 8; kt++) {
                __syncthreads();    // previous compute done, LDS free
                la[skk2 * 68 + sr] = pa.x; la[(skk2 + 1) * 68 + sr] = pa.y;
                lb[skk2 * 68 + sr] = pb.x; lb[(skk2 + 1) * 68 + sr] = pb.y;
                if (kt < 7) {       // prefetch next chunk; latency hides under compute
                    const int k0 = kc * 256 + (kt + 1) * 32;
                    pa = *(const float2*)&xh[(size_t)sr * 2048 + k0 + skk2];
                    const int kg = k0 + skk2;
                    const float* src = (kg < 1536) ? &W_ih[(size_t)(j0 + sr) * 2048 + kg]
                                                   : &W_hh[(size_t)(j0 + sr) * 512 + kg - 1536];
                    pb = *(const float2*)src;
                }
                __syncthreads();
#pragma unroll
                for (int kq = 0; kq < 8; kq++) {
                    const int kk = gq * 8 + kq;
                    float av[4], bv[4];
                    *(float4*)av = *(const float4*)&la[kk * 68 + ty * 4];
                    *(float4*)bv = *(const float4*)&lb[kk * 68 + tx * 4];
#pragma unroll
                    for (int i = 0; i < 4; i++)
#pragma unroll
                        for (int jj = 0; jj < 4; jj++) acc[i][jj] += av[i] * bv[jj];
                }
            }
#pragma unroll
            for (int i = 0; i < 4; i++)
#pragma unroll
                for (int jj = 0; jj < 4; jj++)
                    gpart[(size_t)((kc * 4 + gq) * 64 + ty * 4 + i) * 2048 + j0 + tx * 4 + jj]
                        = acc[i][jj];
        }
        grid.sync();    // gpart visible for next step's update
    }

    // ---- final LSTM update (gates of t=31) -> h_out row 31 ----
    if (blk < 64) {
        for (int idx = tid; idx < 2048; idx += 1024) {
            float s = emb_part[(size_t)(31 * 64 + n) * 2048 + idx];
#pragma unroll 8
            for (int s32 = 0; s32 < 32; s32++)
                s += gpart[(size_t)(s32 * 64 + n) * 2048 + idx];
            gbuf[idx] = s;
        }
        __syncthreads();
        if (tid < 512) {
            float cold = cbuf[(size_t)n * 512 + tid];
            float cn = sigf(gbuf[512 + tid]) * cold + sigf(gbuf[tid]) * tanhf(gbuf[1024 + tid]);
            float hn = sigf(gbuf[1536 + tid]) * tanhf(cn);
            h_out[(size_t)(31 * 64 + n) * 512 + tid] = hn;
        }
    }
}

extern "C" void kernel_launch(void* const* d_in, const int* in_sizes, int n_in,
                              void* d_out, int out_size, void* d_ws, size_t ws_size,
                              hipStream_t stream)
{
    const float* features = (const float*)d_in[0];
    const int*   captions = (const int*)d_in[1];
    const float* embd_W   = (const float*)d_in[2];
    const float* atk_W    = (const float*)d_in[3];
    const float* atk_b    = (const float*)d_in[4];
    const float* af_W     = (const float*)d_in[5];
    const float* af_b     = (const float*)d_in[6];
    const float* full_W   = (const float*)d_in[7];
    const float* full_b   = (const float*)d_in[8];
    const float* W_ih     = (const float*)d_in[9];
    const float* b_ih     = (const float*)d_in[10];
    const float* W_hh     = (const float*)d_in[11];
    const float* b_hh     = (const float*)d_in[12];
    const float* fc_W     = (const float*)d_in[13];
    const float* fc_b     = (const float*)d_in[14];
    const float* init_Wh  = (const float*)d_in[15];
    const float* init_Wc  = (const float*)d_in[16];
    float* out = (float*)d_out;

    float* ws = (float*)d_ws;
    float* AtkWT    = ws; ws += 512 * 512;       // [k][a]
    float* bcomb    = ws; ws += 2048;
    float* attn_img = ws; ws += 4096 * 512;      // [(n*64+p)][a]
    float* emb_part = ws; ws += 2048 * 2048;     // [(t*64+n)][gate j] includes bcomb
    // ipart (48*64*1024 = 3.15M floats) and gpart (32*64*2048 = 4.19M floats) are
    // disjoint in time (ipart consumed by init_reduce before the loop's first gpart
    // write) -> share one region sized for the larger.
    float* gpart    = ws;
    float* ipart    = ws; ws += 32 * 64 * 2048;
    float* xh       = ws; ws += 64 * 2048;       // [n][ctx 1536 | h 512]
    float* cbuf     = ws; ws += 64 * 512;
    float* h_out    = ws; ws += 2048 * 512;      // [(t*64+n)][h]

    transpose_kernel<<<dim3(16, 16), dim3(32, 8), 0, stream>>>(atk_W, AtkWT, 512, 512, 512);
    prep_bcomb<<<8, 256, 0, stream>>>(b_ih, b_hh, bcomb);

    // attn_img = features @ af_W^T + af_b : M=4096, J=512, K=1536
    gemm_nt<0, 0><<<dim3(32, 8), 256, 0, stream>>>(
        features, 1536, af_W, 1536, nullptr, af_b, attn_img, 512, 512, 1536);
    // emb_part[t*64+n][j] = embd_W[cap[n][t]] @ W_ih[:,1536:]^T + bcomb
    gemm_nt<1, 0><<<dim3(16, 32), 256, 0, stream>>>(
        embd_W, 512, W_ih + 1536, 2048, captions, bcomb, emb_part, 2048, 2048, 512);
    // h0/c0 partials + reduce
    init_gemm<<<dim3(16, 48), 256, 0, stream>>>(features, init_Wh, init_Wc, ipart);
    init_reduce<<<256, 256, 0, stream>>>(ipart, xh, cbuf);

    // ---- fused 32-step loop, single cooperative launch (grid.sync inside) ----
    {
        void* kargs[] = {
            (void*)&features, (void*)&attn_img, (void*)&AtkWT, (void*)&atk_b,
            (void*)&full_W, (void*)&full_b, (void*)&emb_part, (void*)&W_ih,
            (void*)&W_hh, (void*)&gpart, (void*)&xh, (void*)&cbuf, (void*)&h_out
        };
        hipLaunchCooperativeKernel((void*)loop_kernel, dim3(256), dim3(1024),
                                   kargs, 0, stream);
    }

    // preds: M=2048 (t*64+n), J=10000, K=512, remapped store to [n][t][v]
    gemm_nt<0, 1><<<dim3(16, 157), 256, 0, stream>>>(
        h_out, 512, fc_W, 512, nullptr, fc_b, out, 10000, 10000, 512);
}